// Round 4
// baseline (558.655 us; speedup 1.0000x reference)
//
#include <hip/hip_runtime.h>
#include <cstddef>
#include <cstdint>

#define HH 16
#define TT 512
#define LOG2E 1.44269504088896340736f

typedef float v2f __attribute__((ext_vector_type(2)));
typedef float v4f __attribute__((ext_vector_type(4)));

static __device__ __forceinline__ float fexp2(float x){ return __builtin_amdgcn_exp2f(x); }
static __device__ __forceinline__ float frcp (float x){ return __builtin_amdgcn_rcpf(x); }
static __device__ __forceinline__ float frsq (float x){ return __builtin_amdgcn_rsqf(x); }

// tanh(c) = 2/(1+exp(-2c)) - 1 ; saturates correctly (rcp(inf)=0)
static __device__ __forceinline__ float ftanh(float c){
    return frcp(1.0f + fexp2(c * (-2.0f*LOG2E))) * 2.0f - 1.0f;
}

// broadcast within each quad of lanes (single v_mov_b32_dpp)
#if __has_builtin(__builtin_amdgcn_mov_dpp)
template<int CTRL>
static __device__ __forceinline__ float qb(float v){
    return __builtin_bit_cast(float,
        __builtin_amdgcn_mov_dpp(__builtin_bit_cast(int,v), CTRL, 0xF, 0xF, true));
}
#else
template<int CTRL>
static __device__ __forceinline__ float qb(float v){
    return __builtin_bit_cast(float,
        __builtin_amdgcn_update_dpp(0, __builtin_bit_cast(int,v), CTRL, 0xF, 0xF, true));
}
#endif

static __device__ __forceinline__ v2f pkfma(v2f a, v2f b, v2f c){
    return __builtin_elementwise_fma(a, b, c);  // -> v_pk_fma_f32
}

// accumulate a 16-float dot into two v2f partials (8 pk_fma)
static __device__ __forceinline__ void dot16_acc(const v4f* a, const v4f* w, v2f& s0, v2f& s1){
    s0 = pkfma(a[0].lo, w[0].lo, s0);  s1 = pkfma(a[0].hi, w[0].hi, s1);
    s0 = pkfma(a[1].lo, w[1].lo, s0);  s1 = pkfma(a[1].hi, w[1].hi, s1);
    s0 = pkfma(a[2].lo, w[2].lo, s0);  s1 = pkfma(a[2].hi, w[2].hi, s1);
    s0 = pkfma(a[3].lo, w[3].lo, s0);  s1 = pkfma(a[3].hi, w[3].hi, s1);
}

// FIRST dot of an accumulation: fold the bias into s0's first fma and start
// s1 with a pk_mul — removes the accumulator-init v_movs per dot-pair.
static __device__ __forceinline__ void dot16_first(const v4f* a, const v4f* w, v2f bias2,
                                                   v2f& s0, v2f& s1){
    s0 = pkfma(a[0].lo, w[0].lo, bias2);
    s1 = a[0].hi * w[0].hi;            // v_pk_mul_f32
    s0 = pkfma(a[1].lo, w[1].lo, s0);  s1 = pkfma(a[1].hi, w[1].hi, s1);
    s0 = pkfma(a[2].lo, w[2].lo, s0);  s1 = pkfma(a[2].hi, w[2].hi, s1);
    s0 = pkfma(a[3].lo, w[3].lo, s0);  s1 = pkfma(a[3].hi, w[3].hi, s1);
}

static __device__ __forceinline__ void ld4(v4f* dst, const float* p){
    const v4f* q = (const v4f*)p;
    dst[0] = q[0]; dst[1] = q[1]; dst[2] = q[2]; dst[3] = q[3];
}

// Force a wave-uniform pointer into SGPRs so subsequent loads select SMEM
// (s_load): x rows are read by all 64 lanes at the same address, so routing
// them through the scalar cache frees both the VALU and the LDS pipe.
static __device__ __forceinline__ const float* uniform_ptr(const float* p){
    uint64_t v = (uint64_t)p;
    uint32_t lo = __builtin_amdgcn_readfirstlane((uint32_t)v);
    uint32_t hi = __builtin_amdgcn_readfirstlane((uint32_t)(v >> 32));
    return (const float*)(((uint64_t)hi << 32) | (uint64_t)lo);
}

// One wave per batch element. Lane l owns gate g=l&3 of hidden unit k=l>>2.
// Software-pipelined: layer 1 runs ONE timestep ahead of layer 2.
// x is fetched via the SCALAR pipe (wave-uniform s_load, prefetched 1 step
// ahead); LDS carries only the h1/h2 quad->wave broadcast (8 ds_read_b128 +
// 2 ds_write per step, all uniform-address broadcasts).
__global__ __launch_bounds__(256, 4) void lstm_fused_kernel(
    const float* __restrict__ x,
    const float* __restrict__ W_ih0, const float* __restrict__ W_hh0,
    const float* __restrict__ b_ih0, const float* __restrict__ b_hh0,
    const float* __restrict__ W_ih1, const float* __restrict__ W_hh1,
    const float* __restrict__ b_ih1, const float* __restrict__ b_hh1,
    const float* __restrict__ W_proj, const float* __restrict__ b_proj,
    const float* __restrict__ ln_g, const float* __restrict__ ln_b,
    float* __restrict__ out)
{
    const int lane = threadIdx.x & 63;
    const int wave = threadIdx.x >> 6;
    const int b    = blockIdx.x * 4 + wave;

    const int g   = lane & 3;        // 0=i 1=f 2=g 3=o
    const int k   = lane >> 2;       // hidden unit 0..15
    const int row = g * HH + k;      // row in [4H,H] weights (PyTorch order)

    // per-wave LDS: h1[16] + h2[16] (padded to 64 floats/wave)
    __shared__ float sh[4 * 64];
    float* h1w = sh + wave * 64;
    float* h2w = h1w + 32;

    // activation input scale: sigmoid lanes -log2e, tanh(g) lane -2log2e.
    const bool  isg   = (g == 2);
    const float sc_in = isg ? (-2.0f * LOG2E) : (-LOG2E);

    // ---- weights into VGPRs as v4f, PRE-SCALED by sc_in ----
    v4f wih0[4], whh0[4], wih1[4], whh1[4];
#pragma unroll
    for (int q = 0; q < 4; ++q) {
        wih0[q] = ((const v4f*)(W_ih0 + row * HH))[q] * sc_in;
        whh0[q] = ((const v4f*)(W_hh0 + row * HH))[q] * sc_in;
        wih1[q] = ((const v4f*)(W_ih1 + row * HH))[q] * sc_in;
        whh1[q] = ((const v4f*)(W_hh1 + row * HH))[q] * sc_in;
    }
    const v2f bias0v = {(b_ih0[row] + b_hh0[row]) * sc_in, 0.f};
    const v2f bias1v = {(b_ih1[row] + b_hh1[row]) * sc_in, 0.f};

    // wave-uniform x pointer -> scalar loads
    const float* xg = uniform_ptr(x + (size_t)b * TT * HH);

    // ================= prologue =================
    v4f xa[4];
    ld4(xa, xg);                               // x(0), scalar

    float cs1, cs2 = 0.0f;                     // cs = -2*log2e * c
    v4f h1a[4], h2a[4];
#pragma unroll
    for (int q = 0; q < 4; ++q) h2a[q] = (v4f)(0.f);

    // layer-1 step 0 (h1(-1) = 0: skip hh dot)
    {
        v2f p0, p1;
        dot16_first(xa, wih0, bias0v, p0, p1);
        v2f ps = p0 + p1;
        float a1 = ps.x + ps.y;
        float r1 = frcp(1.0f + fexp2(a1));
        float i1 = qb<0x00>(r1), g1 = qb<0xAA>(r1), o1 = qb<0xFF>(r1);
        float gs1 = __builtin_fmaf(g1, -4.0f*LOG2E, 2.0f*LOG2E);  // -2L*tanh-gate
        cs1 = i1 * gs1;
        float h1n = o1 * (frcp(1.0f + fexp2(cs1)) * 2.0f - 1.0f);
        h1w[k] = h1n;
        ld4(h1a, h1w);                         // broadcast h1(0)
        ld4(xa, xg + HH);                      // x(1), scalar
    }

    // ================= main loop =================
    // iter j: layer1 computes h1(j+1) [xa=x(j+1), h1a=h1(j)];
    //         layer2 computes h2(j)   [h1a=h1(j), h2a=h2(j-1)]
#pragma unroll 8
    for (int j = 0; j < TT; ++j) {
        // ---- layer 1, step j+1 ----
        v2f p0, p1;
        dot16_first(xa, wih0, bias0v, p0, p1);
        dot16_acc(h1a, whh0, p0, p1);
        v2f ps = p0 + p1;
        float a1 = ps.x + ps.y;
        float r1 = frcp(1.0f + fexp2(a1));
        float i1 = qb<0x00>(r1), f1 = qb<0x55>(r1);
        float g1 = qb<0xAA>(r1), o1 = qb<0xFF>(r1);
        float gs1 = __builtin_fmaf(g1, -4.0f*LOG2E, 2.0f*LOG2E);
        cs1 = __builtin_fmaf(f1, cs1, i1 * gs1);
        float h1n = o1 * (frcp(1.0f + fexp2(cs1)) * 2.0f - 1.0f);
        h1w[k] = h1n;                          // publish h1(j+1)

        // ---- layer 2 part A: h1(j) · W_ih1 (last use of h1a) ----
        v2f q0, q1;
        dot16_first(h1a, wih1, bias1v, q0, q1);

        ld4(h1a, h1w);                         // broadcast h1(j+1)  [next iter]
        const int jn = (j + 2 < TT) ? (j + 2) : (TT - 1);
        ld4(xa, xg + jn * HH);                 // scalar prefetch x(j+2) [next iter]

        // ---- layer 2 part B: h2(j-1) · W_hh1 ----
        dot16_acc(h2a, whh1, q0, q1);
        v2f qs = q0 + q1;
        float a2 = qs.x + qs.y;
        float r2 = frcp(1.0f + fexp2(a2));
        float i2 = qb<0x00>(r2), f2 = qb<0x55>(r2);
        float g2 = qb<0xAA>(r2), o2 = qb<0xFF>(r2);
        float gs2 = __builtin_fmaf(g2, -4.0f*LOG2E, 2.0f*LOG2E);
        cs2 = __builtin_fmaf(f2, cs2, i2 * gs2);
        float h2n = o2 * (frcp(1.0f + fexp2(cs2)) * 2.0f - 1.0f);
        h2w[k] = h2n;                          // publish h2(j)
        ld4(h2a, h2w);                         // broadcast h2(j)    [next iter]
    }

    // ---- epilogue: z = h2(T-1) @ W_proj^T + b_proj ; LayerNorm ; tanh ----
    const int u = lane & 15;   // output unit (replicated x4 across the wave)
    v4f wp[4];
#pragma unroll
    for (int q = 0; q < 4; ++q) wp[q] = ((const v4f*)(W_proj + u * HH))[q];
    const v2f bpv = {b_proj[u], 0.f};
    v2f z0, z1;
    dot16_first(h2a, wp, bpv, z0, z1);
    v2f zs = z0 + z1;
    float z = zs.x + zs.y;

    // stats across the 16-lane group (xor masks 1,2,4,8 stay in-group)
    float sacc = z;
    sacc += __shfl_xor(sacc, 1); sacc += __shfl_xor(sacc, 2);
    sacc += __shfl_xor(sacc, 4); sacc += __shfl_xor(sacc, 8);
    const float mu = sacc * (1.0f / 16.0f);

    const float d = z - mu;
    float q2 = d * d;
    q2 += __shfl_xor(q2, 1); q2 += __shfl_xor(q2, 2);
    q2 += __shfl_xor(q2, 4); q2 += __shfl_xor(q2, 8);
    const float var = q2 * (1.0f / 16.0f);

    const float rs  = frsq(var + 1e-5f);
    const float y   = d * rs * ln_g[u] + ln_b[u];
    const float res = ftanh(y);

    if (lane < 16) out[(size_t)b * HH + lane] = res;
}

extern "C" void kernel_launch(void* const* d_in, const int* in_sizes, int n_in,
                              void* d_out, int out_size, void* d_ws, size_t ws_size,
                              hipStream_t stream) {
    const float* x      = (const float*)d_in[0];
    const float* W_ih0  = (const float*)d_in[1];
    const float* W_hh0  = (const float*)d_in[2];
    const float* b_ih0  = (const float*)d_in[3];
    const float* b_hh0  = (const float*)d_in[4];
    const float* W_ih1  = (const float*)d_in[5];
    const float* W_hh1  = (const float*)d_in[6];
    const float* b_ih1  = (const float*)d_in[7];
    const float* b_hh1  = (const float*)d_in[8];
    const float* W_proj = (const float*)d_in[9];
    const float* b_proj = (const float*)d_in[10];
    const float* ln_g   = (const float*)d_in[11];
    const float* ln_b   = (const float*)d_in[12];
    float* out = (float*)d_out;

    const int B = in_sizes[0] / (TT * HH);   // 4096
    dim3 grid(B / 4), block(256);            // one wave per batch element
    hipLaunchKernelGGL(lstm_fused_kernel, grid, block, 0, stream,
                       x, W_ih0, W_hh0, b_ih0, b_hh0,
                       W_ih1, W_hh1, b_ih1, b_hh1,
                       W_proj, b_proj, ln_g, ln_b, out);
}

// Round 5
// 470.571 us; speedup vs baseline: 1.1872x; 1.1872x over previous
//
#include <hip/hip_runtime.h>
#include <cstddef>

#define HH 16
#define TT 512
#define STG 16           // timesteps per LDS x-stage
#define NSTG (TT / STG)  // 32 stages
#define LOG2E 1.44269504088896340736f

typedef float v2f __attribute__((ext_vector_type(2)));
typedef float v4f __attribute__((ext_vector_type(4)));

static __device__ __forceinline__ float fexp2(float x){ return __builtin_amdgcn_exp2f(x); }
static __device__ __forceinline__ float frcp (float x){ return __builtin_amdgcn_rcpf(x); }
static __device__ __forceinline__ float frsq (float x){ return __builtin_amdgcn_rsqf(x); }

// tanh(c) = 2/(1+exp(-2c)) - 1 ; saturates correctly (rcp(inf)=0)
static __device__ __forceinline__ float ftanh(float c){
    return frcp(1.0f + fexp2(c * (-2.0f*LOG2E))) * 2.0f - 1.0f;
}

// broadcast within each quad of lanes (single v_mov_b32_dpp)
#if __has_builtin(__builtin_amdgcn_mov_dpp)
template<int CTRL>
static __device__ __forceinline__ float qb(float v){
    return __builtin_bit_cast(float,
        __builtin_amdgcn_mov_dpp(__builtin_bit_cast(int,v), CTRL, 0xF, 0xF, true));
}
#else
template<int CTRL>
static __device__ __forceinline__ float qb(float v){
    return __builtin_bit_cast(float,
        __builtin_amdgcn_update_dpp(0, __builtin_bit_cast(int,v), CTRL, 0xF, 0xF, true));
}
#endif

static __device__ __forceinline__ v2f pkfma(v2f a, v2f b, v2f c){
    return __builtin_elementwise_fma(a, b, c);  // -> v_pk_fma_f32
}

// accumulate a 16-float dot into two v2f partials (8 pk_fma)
static __device__ __forceinline__ void dot16_acc(const v4f* a, const v4f* w, v2f& s0, v2f& s1){
    s0 = pkfma(a[0].lo, w[0].lo, s0);  s1 = pkfma(a[0].hi, w[0].hi, s1);
    s0 = pkfma(a[1].lo, w[1].lo, s0);  s1 = pkfma(a[1].hi, w[1].hi, s1);
    s0 = pkfma(a[2].lo, w[2].lo, s0);  s1 = pkfma(a[2].hi, w[2].hi, s1);
    s0 = pkfma(a[3].lo, w[3].lo, s0);  s1 = pkfma(a[3].hi, w[3].hi, s1);
}

// FIRST dot of an accumulation: fold the (loop-invariant) bias vector into
// s0's first fma and start s1 with a pk_mul — removes the accumulator-init
// v_movs per dot-pair.
static __device__ __forceinline__ void dot16_first(const v4f* a, const v4f* w, v2f bias2,
                                                   v2f& s0, v2f& s1){
    s0 = pkfma(a[0].lo, w[0].lo, bias2);
    s1 = a[0].hi * w[0].hi;            // v_pk_mul_f32
    s0 = pkfma(a[1].lo, w[1].lo, s0);  s1 = pkfma(a[1].hi, w[1].hi, s1);
    s0 = pkfma(a[2].lo, w[2].lo, s0);  s1 = pkfma(a[2].hi, w[2].hi, s1);
    s0 = pkfma(a[3].lo, w[3].lo, s0);  s1 = pkfma(a[3].hi, w[3].hi, s1);
}

static __device__ __forceinline__ void ld4(v4f* dst, const float* p){
    const v4f* q = (const v4f*)p;
    dst[0] = q[0]; dst[1] = q[1]; dst[2] = q[2]; dst[3] = q[3];
}

// One wave per batch element. Lane l owns gate g=l&3 of hidden unit k=l>>2.
// Software-pipelined: layer 1 runs ONE timestep ahead of layer 2 (R1-proven
// structure: LDS x-staging ping-pong, mov_dpp quad broadcasts, 4 waves/SIMD).
//
// New this round:
//  * dot16_first bias-fold (kills accumulator-init v_movs).
//  * prologue s_sleep skew: the 4 waves resident on one SIMD come from 4
//    different blocks running identical code — their stall windows align,
//    causing ~24% all-stalled idle. A 0/128/256/384-cycle one-time skew
//    de-phases them so round-robin issue fills each wave's stalls with the
//    other waves' FMA-dense regions. Costs zero issue slots.
__global__ __launch_bounds__(256, 4) void lstm_fused_kernel(
    const float* __restrict__ x,
    const float* __restrict__ W_ih0, const float* __restrict__ W_hh0,
    const float* __restrict__ b_ih0, const float* __restrict__ b_hh0,
    const float* __restrict__ W_ih1, const float* __restrict__ W_hh1,
    const float* __restrict__ b_ih1, const float* __restrict__ b_hh1,
    const float* __restrict__ W_proj, const float* __restrict__ b_proj,
    const float* __restrict__ ln_g, const float* __restrict__ ln_b,
    float* __restrict__ out)
{
    const int lane = threadIdx.x & 63;
    const int wave = threadIdx.x >> 6;
    const int b    = blockIdx.x * 4 + wave;

    const int g   = lane & 3;        // 0=i 1=f 2=g 3=o
    const int k   = lane >> 2;       // hidden unit 0..15
    const int row = g * HH + k;      // row in [4H,H] weights (PyTorch order)

    // de-phase waves that share a SIMD (they come from different blocks;
    // wave-uniform branch, one-time cost)
    {
        const int ph = blockIdx.x & 3;
        if      (ph == 1) __builtin_amdgcn_s_sleep(2);   // ~128 cyc
        else if (ph == 2) __builtin_amdgcn_s_sleep(4);   // ~256 cyc
        else if (ph == 3) __builtin_amdgcn_s_sleep(6);   // ~384 cyc
    }

    // per-wave LDS: two 256-float x-stages (ping-pong) + h1[16] + h2[16]
    __shared__ float sh[4 * 544];
    float* xb0 = sh + wave * 544;
    float* xb1 = xb0 + 256;
    float* h1w = xb1 + 256;
    float* h2w = h1w + 16;

    // activation input scale: sigmoid lanes -log2e, tanh(g) lane -2log2e.
    const bool  isg   = (g == 2);
    const float sc_in = isg ? (-2.0f * LOG2E) : (-LOG2E);

    // ---- weights into VGPRs as v4f, PRE-SCALED by sc_in ----
    v4f wih0[4], whh0[4], wih1[4], whh1[4];
#pragma unroll
    for (int q = 0; q < 4; ++q) {
        wih0[q] = ((const v4f*)(W_ih0 + row * HH))[q] * sc_in;
        whh0[q] = ((const v4f*)(W_hh0 + row * HH))[q] * sc_in;
        wih1[q] = ((const v4f*)(W_ih1 + row * HH))[q] * sc_in;
        whh1[q] = ((const v4f*)(W_hh1 + row * HH))[q] * sc_in;
    }
    const v2f bias0v = {(b_ih0[row] + b_hh0[row]) * sc_in, 0.f};  // loop-invariant
    const v2f bias1v = {(b_ih1[row] + b_hh1[row]) * sc_in, 0.f};

    const float* xg = x + (size_t)b * TT * HH;

    // ================= prologue =================
    v4f xs = *(const v4f*)(xg + lane * 4);     // global stage 0
    *(v4f*)(xb0 + lane * 4) = xs;              // LDS stage 0
    xs = *(const v4f*)(xg + 256 + lane * 4);   // prefetch global stage 1

    v4f xa[4];
    ld4(xa, xb0);                              // broadcast x(0)

    float cs1, cs2 = 0.0f;                     // cs = -2*log2e * c
    v4f h1a[4], h2a[4];
#pragma unroll
    for (int q = 0; q < 4; ++q) h2a[q] = (v4f)(0.f);

    // layer-1 step 0 (h1(-1) = 0: skip hh dot)
    {
        v2f p0, p1;
        dot16_first(xa, wih0, bias0v, p0, p1);
        v2f ps = p0 + p1;
        float a1 = ps.x + ps.y;
        float r1 = frcp(1.0f + fexp2(a1));
        float i1 = qb<0x00>(r1), g1 = qb<0xAA>(r1), o1 = qb<0xFF>(r1);
        float gs1 = __builtin_fmaf(g1, -4.0f*LOG2E, 2.0f*LOG2E);  // -2L*tanh-gate
        cs1 = i1 * gs1;
        float h1n = o1 * (frcp(1.0f + fexp2(cs1)) * 2.0f - 1.0f);
        h1w[k] = h1n;
        ld4(h1a, h1w);                         // broadcast h1(0)
        ld4(xa, xb0 + HH);                     // broadcast x(1)
    }

    // ================= main loop =================
    // iter t: layer1 computes h1(t+1) [xa=x(t+1), h1a=h1(t)];
    //         layer2 computes h2(t)   [h1a=h1(t), h2a=h2(t-1)]
    for (int s = 0; s < NSTG; ++s) {
        float* cur = (s & 1) ? xb1 : xb0;
        float* nxt = (s & 1) ? xb0 : xb1;

        *(v4f*)(nxt + lane * 4) = xs;          // LDS stage s+1
        const int sp = (s + 2 < NSTG) ? (s + 2) : (NSTG - 1);
        xs = *(const v4f*)(xg + (size_t)sp * 256 + lane * 4);  // prefetch s+2

#pragma unroll
        for (int ti = 0; ti < STG; ++ti) {
            // ---- layer 1, step t+1 ----
            v2f p0, p1;
            dot16_first(xa, wih0, bias0v, p0, p1);
            dot16_acc(h1a, whh0, p0, p1);
            v2f ps = p0 + p1;
            float a1 = ps.x + ps.y;
            float r1 = frcp(1.0f + fexp2(a1));
            float i1 = qb<0x00>(r1), f1 = qb<0x55>(r1);
            float g1 = qb<0xAA>(r1), o1 = qb<0xFF>(r1);
            float gs1 = __builtin_fmaf(g1, -4.0f*LOG2E, 2.0f*LOG2E);
            cs1 = __builtin_fmaf(f1, cs1, i1 * gs1);
            float h1n = o1 * (frcp(1.0f + fexp2(cs1)) * 2.0f - 1.0f);
            h1w[k] = h1n;                      // publish h1(t+1)

            // ---- layer 2 part A: h1(t) · W_ih1 (last use of h1a) ----
            v2f q0, q1;
            dot16_first(h1a, wih1, bias1v, q0, q1);

            ld4(h1a, h1w);                     // broadcast h1(t+1)  [next iter]
            // broadcast x(t+2) [next iter]; ti=14,15 cross into next stage
            ld4(xa, (ti <= 13) ? (cur + (ti + 2) * HH) : (nxt + (ti - 14) * HH));

            // ---- layer 2 part B: h2(t-1) · W_hh1 ----
            dot16_acc(h2a, whh1, q0, q1);
            v2f qs = q0 + q1;
            float a2 = qs.x + qs.y;
            float r2 = frcp(1.0f + fexp2(a2));
            float i2 = qb<0x00>(r2), f2 = qb<0x55>(r2);
            float g2 = qb<0xAA>(r2), o2 = qb<0xFF>(r2);
            float gs2 = __builtin_fmaf(g2, -4.0f*LOG2E, 2.0f*LOG2E);
            cs2 = __builtin_fmaf(f2, cs2, i2 * gs2);
            float h2n = o2 * (frcp(1.0f + fexp2(cs2)) * 2.0f - 1.0f);
            h2w[k] = h2n;                      // publish h2(t)
            ld4(h2a, h2w);                     // broadcast h2(t)    [next iter]
        }
    }

    // ---- epilogue: z = h2(T-1) @ W_proj^T + b_proj ; LayerNorm ; tanh ----
    const int u = lane & 15;   // output unit (replicated x4 across the wave)
    v4f wp[4];
#pragma unroll
    for (int q = 0; q < 4; ++q) wp[q] = ((const v4f*)(W_proj + u * HH))[q];
    const v2f bpv = {b_proj[u], 0.f};
    v2f z0, z1;
    dot16_first(h2a, wp, bpv, z0, z1);
    v2f zs = z0 + z1;
    float z = zs.x + zs.y;

    // stats across the 16-lane group (xor masks 1,2,4,8 stay in-group)
    float sacc = z;
    sacc += __shfl_xor(sacc, 1); sacc += __shfl_xor(sacc, 2);
    sacc += __shfl_xor(sacc, 4); sacc += __shfl_xor(sacc, 8);
    const float mu = sacc * (1.0f / 16.0f);

    const float d = z - mu;
    float q2 = d * d;
    q2 += __shfl_xor(q2, 1); q2 += __shfl_xor(q2, 2);
    q2 += __shfl_xor(q2, 4); q2 += __shfl_xor(q2, 8);
    const float var = q2 * (1.0f / 16.0f);

    const float rs  = frsq(var + 1e-5f);
    const float y   = d * rs * ln_g[u] + ln_b[u];
    const float res = ftanh(y);

    if (lane < 16) out[(size_t)b * HH + lane] = res;
}

extern "C" void kernel_launch(void* const* d_in, const int* in_sizes, int n_in,
                              void* d_out, int out_size, void* d_ws, size_t ws_size,
                              hipStream_t stream) {
    const float* x      = (const float*)d_in[0];
    const float* W_ih0  = (const float*)d_in[1];
    const float* W_hh0  = (const float*)d_in[2];
    const float* b_ih0  = (const float*)d_in[3];
    const float* b_hh0  = (const float*)d_in[4];
    const float* W_ih1  = (const float*)d_in[5];
    const float* W_hh1  = (const float*)d_in[6];
    const float* b_ih1  = (const float*)d_in[7];
    const float* b_hh1  = (const float*)d_in[8];
    const float* W_proj = (const float*)d_in[9];
    const float* b_proj = (const float*)d_in[10];
    const float* ln_g   = (const float*)d_in[11];
    const float* ln_b   = (const float*)d_in[12];
    float* out = (float*)d_out;

    const int B = in_sizes[0] / (TT * HH);   // 4096
    dim3 grid(B / 4), block(256);            // one wave per batch element
    hipLaunchKernelGGL(lstm_fused_kernel, grid, block, 0, stream,
                       x, W_ih0, W_hh0, b_ih0, b_hh0,
                       W_ih1, W_hh1, b_ih1, b_hh1,
                       W_proj, b_proj, ln_g, ln_b, out);
}